// Round 13
// baseline (227.888 us; speedup 1.0000x reference)
//
#include <hip/hip_runtime.h>
#include <cstdint>
#include <cstddef>

#define CIN     16
#define CHID    16
#define T_DIM   31
#define HW_     16384            // 128*128
#define CH_STRIDE 507904         // 31*128*128
#define TILE_H  4
#define TILE_W  32
#define SH      6                // TILE_H + 2
#define SW      34               // TILE_W + 2
#define SPOS    (SH * SW)        // 204 positions
#define PSTR    24               // shorts per position (48B) — champion value
#define SLICE_SH (SPOS * PSTR)   // 4896 shorts

typedef short bf16x8 __attribute__((ext_vector_type(8)));
typedef float f32x16 __attribute__((ext_vector_type(16)));

__device__ __forceinline__ unsigned bf16_bits(float x) {
  unsigned u = __builtin_bit_cast(unsigned, x);
  u += 0x7FFFu + ((u >> 16) & 1u);
  return u >> 16;
}
__device__ __forceinline__ unsigned cvt_pk_bf16(float lo, float hi) {
  unsigned r;
  asm("v_cvt_pk_bf16_f32 %0, %1, %2" : "=v"(r) : "v"(lo), "v"(hi));
  return r;
}

#define MFMA(W, X, C) __builtin_amdgcn_mfma_f32_32x32x16_bf16((W), (X), (C), 0, 0, 0)

__global__ __launch_bounds__(256, 2)
void qrnn3d_v13(const float* __restrict__ in, const float* __restrict__ Wg,
                const float* __restrict__ bg, float* __restrict__ out) {
  __shared__ __align__(16) short xs[3][SLICE_SH];   // 29,376 B

  const int tid = threadIdx.x;
  const int bid = blockIdx.x;
  // bijective XCD-chunked swizzle (512 blocks, 512%8==0)
  const int lin  = ((bid & 7) << 6) | (bid >> 3);
  const int b    = lin >> 7;                 // 4 batches x 128 tiles
  const int tile = lin & 127;
  const int h0   = (tile >> 2) * TILE_H;     // 32 h-tiles
  const int w0   = (tile & 3) * TILE_W;      // 4 w-tiles

  const int lane = tid & 63;
  const int wid  = tid >> 6;                 // wave 0..3 -> output row
  const int col  = lane & 31;                // MFMA N column / oc for A-frag
  const int half = lane >> 5;                // K half (ci 0-7 / 8-15)

  // ---- weights -> 27 A-frags ----
  bf16x8 wfrag[27];
#pragma unroll
  for (int tau = 0; tau < 27; ++tau) {
    bf16x8 f;
#pragma unroll
    for (int j = 0; j < 8; ++j)
      f[j] = (short)bf16_bits(Wg[col * 432 + (half * 8 + j) * 27 + tau]);
    wfrag[tau] = f;
  }

  // ---- bias-preloaded accumulator template + t-invariant store offsets ----
  f32x16 accInit;
  int voff[8];
#pragma unroll
  for (int r = 0; r < 8; ++r) {
    int oc = (r & 3) + 8 * (r >> 2) + 4 * half;          // 0..15
    accInit[r]     = bg[oc];
    accInit[r + 8] = bg[oc + 16];
    voff[r] = (b * CHID + oc) * CH_STRIDE + (h0 + wid) * 128 + (w0 + col);
  }

  // ---- staging precompute (t-invariant): unit = (pos, ci-quad) ----
  const float* gp[4];
  int  lso[4];
  bool stv[4], ldv[4];
#pragma unroll
  for (int i = 0; i < 4; ++i) {
    int p   = tid + i * 256;         // [0,1024)
    int q   = p & 15;
    int c4  = (p >> 4) & 3;
    int j   = p >> 6;
    int pos = j * 16 + q;            // [0,256)
    stv[i]  = (pos < SPOS);
    int hh  = pos / SW;
    int ww  = pos - hh * SW;
    int gh  = h0 + hh - 1, gw = w0 + ww - 1;
    ldv[i]  = stv[i] && ((unsigned)gh < 128u) && ((unsigned)gw < 128u);
    int sp  = ldv[i] ? (gh * 128 + gw) : 0;
    gp[i]   = in + (size_t)(b * CIN + c4 * 4) * CH_STRIDE + sp;
    lso[i]  = pos * PSTR + c4 * 4;   // shorts
  }

#define LOADV(tz, vv)                                                \
  do {                                                               \
    if ((tz) <= 30) {                                                \
      const int toff = (tz) * HW_;                                   \
      _Pragma("unroll")                                              \
      for (int i = 0; i < 4; ++i) {                                  \
        _Pragma("unroll")                                            \
        for (int k = 0; k < 4; ++k)                                  \
          vv[i][k] = ldv[i] ? gp[i][toff + k * CH_STRIDE] : 0.0f;    \
      }                                                              \
    } else {                                                         \
      _Pragma("unroll")                                              \
      for (int i = 0; i < 4; ++i) {                                  \
        _Pragma("unroll")                                            \
        for (int k = 0; k < 4; ++k) vv[i][k] = 0.0f;                 \
      }                                                              \
    }                                                                \
  } while (0)

#define STOREV(vv, slot)                                             \
  do {                                                               \
    short* dst = &xs[(slot)][0];                                     \
    _Pragma("unroll")                                                \
    for (int i = 0; i < 4; ++i) {                                    \
      if (stv[i]) {                                                  \
        uint2 u;                                                     \
        u.x = cvt_pk_bf16(vv[i][0], vv[i][1]);                       \
        u.y = cvt_pk_bf16(vv[i][2], vv[i][3]);                       \
        *reinterpret_cast<uint2*>(dst + lso[i]) = u;                 \
      }                                                              \
    }                                                                \
  } while (0)

  // ---- compute geometry: 9 LDS read offsets (kh,kw), t-invariant ----
  int lb[9];
#pragma unroll
  for (int kh = 0; kh < 3; ++kh)
#pragma unroll
    for (int kw = 0; kw < 3; ++kw)
      lb[kh * 3 + kw] = ((wid + kh) * SW + (col + kw)) * PSTR + half * 8;

#define RD(SLOT, U) (*(const bf16x8*)(&xs[(SLOT)][0] + lb[(U)]))

  float hst[8];
#pragma unroll
  for (int r = 0; r < 8; ++r) hst[r] = 0.0f;

  const float C_TANH = 2.8853900817779268f;   // 2*log2(e)
  const float C_SIG  = 1.4426950408889634f;   // log2(e)

#define EPI(T, ACC)                                                  \
  do {                                                               \
    float* outT_ = out + (size_t)(T) * HW_;                          \
    _Pragma("unroll")                                                \
    for (int r_ = 0; r_ < 8; ++r_) {                                 \
      float zg_ = (ACC)[r_], fg_ = (ACC)[r_ + 8];                    \
      float ez_ = exp2f(zg_ * C_TANH);                               \
      float z_  = __builtin_fmaf(-2.0f, __builtin_amdgcn_rcpf(ez_ + 1.0f), 1.0f); \
      float ef_ = exp2f(-fg_ * C_SIG);                               \
      float f_  = __builtin_amdgcn_rcpf(1.0f + ef_);                 \
      float h_  = __builtin_fmaf(f_, hst[r_] - z_, z_);              \
      hst[r_]   = h_;                                                \
      outT_[voff[r_]] = h_;                                          \
    }                                                                \
  } while (0)

  // Streaming 3-tap FIR step: stage slice T+2, read slice T+1 ONCE (9 reads),
  // feed 3 pending accumulators (kd=0 -> new out[T+2], kd=1 -> out[T+1],
  // kd=2 -> completes out[T]), then epilogue out[T].
#define STEP(T, SRD, SWR, AC, AM, AN, VCUR, VNXT)                    \
  do {                                                               \
    LOADV((T) + 3, VNXT);                                            \
    STOREV(VCUR, SWR);                                               \
    __syncthreads();                                                 \
    bf16x8 xb_[9];                                                   \
    _Pragma("unroll")                                                \
    for (int u_ = 0; u_ < 9; ++u_) xb_[u_] = RD(SRD, u_);            \
    AN = MFMA(wfrag[0], xb_[0], accInit);                            \
    _Pragma("unroll")                                                \
    for (int u_ = 1; u_ < 9; ++u_) AN = MFMA(wfrag[u_], xb_[u_], AN);\
    _Pragma("unroll")                                                \
    for (int u_ = 0; u_ < 9; ++u_) AM = MFMA(wfrag[9 + u_], xb_[u_], AM); \
    _Pragma("unroll")                                                \
    for (int u_ = 0; u_ < 9; ++u_) AC = MFMA(wfrag[18 + u_], xb_[u_], AC); \
    EPI(T, AC);                                                      \
  } while (0)

  f32x16 A0, A1, A2;
  float vA[4][4], vB[4][4];

  // ---- prologue: slice s -> slot s%3; slice 2 kept in vA for step 0 ----
  LOADV(0, vA); STOREV(vA, 0);
  LOADV(1, vB); STOREV(vB, 1);
  LOADV(2, vA);
  __syncthreads();
  // virtual step -1: slice 0 (slot 0) -> out[0] (kd=1) into A0, out[1] (kd=0) into A1
  {
    bf16x8 xb_[9];
#pragma unroll
    for (int u = 0; u < 9; ++u) xb_[u] = RD(0, u);
    A0 = MFMA(wfrag[9], xb_[0], accInit);
#pragma unroll
    for (int u = 1; u < 9; ++u) A0 = MFMA(wfrag[9 + u], xb_[u], A0);
    A1 = MFMA(wfrag[0], xb_[0], accInit);
#pragma unroll
    for (int u = 1; u < 9; ++u) A1 = MFMA(wfrag[u], xb_[u], A1);
  }
  // A2 is first written (seeded from accInit) at step 0 as the "new" acc.

  // ---- main loop: 6-step unroll (LCM of 3-slot ring and 2-reg ping-pong) ----
#pragma unroll 1
  for (int tb = 0; tb < 30; tb += 6) {
    STEP(tb + 0, 1, 2, A0, A1, A2, vA, vB);
    STEP(tb + 1, 2, 0, A1, A2, A0, vB, vA);
    STEP(tb + 2, 0, 1, A2, A0, A1, vA, vB);
    STEP(tb + 3, 1, 2, A0, A1, A2, vB, vA);
    STEP(tb + 4, 2, 0, A1, A2, A0, vA, vB);
    STEP(tb + 5, 0, 1, A2, A0, A1, vB, vA);
  }
  // tail: out[30] completed by kd=0 (slice 29, t=28) + kd=1 (slice 30, t=29);
  // kd=2 would be slice 31 = zeros -> skip.
  EPI(30, A0);

#undef LOADV
#undef STOREV
#undef RD
#undef EPI
#undef STEP
}

extern "C" void kernel_launch(void* const* d_in, const int* in_sizes, int n_in,
                              void* d_out, int out_size, void* d_ws, size_t ws_size,
                              hipStream_t stream) {
  const float* in = (const float*)d_in[0];
  const float* Wg = (const float*)d_in[1];
  const float* bg = (const float*)d_in[2];
  float* out      = (float*)d_out;
  (void)in_sizes; (void)n_in; (void)out_size; (void)d_ws; (void)ws_size;
  qrnn3d_v13<<<dim3(512), dim3(256), 0, stream>>>(in, Wg, bg, out);
}

// Round 14
// 125.610 us; speedup vs baseline: 1.8143x; 1.8143x over previous
//
#include <hip/hip_runtime.h>
#include <cstdint>
#include <cstddef>

#define CIN     16
#define CHID    16
#define T_DIM   31
#define HW_     16384            // 128*128
#define CH_STRIDE 507904         // 31*128*128
#define TILE_H  4
#define TILE_W  32
#define SH      6                // TILE_H + 2
#define SW      34               // TILE_W + 2
#define SPOS    (SH * SW)        // 204 positions
#define PSTR    24               // 48B/position: pos*48 and half*16 both 16B-aligned => clean ds_read_b128
#define SLICE_SH (SPOS * PSTR)   // 4896 shorts

typedef short bf16x8 __attribute__((ext_vector_type(8)));
typedef float f32x16 __attribute__((ext_vector_type(16)));

__device__ __forceinline__ unsigned bf16_bits(float x) {
  unsigned u = __builtin_bit_cast(unsigned, x);
  u += 0x7FFFu + ((u >> 16) & 1u);
  return u >> 16;
}
__device__ __forceinline__ unsigned cvt_pk_bf16(float lo, float hi) {
  unsigned r;
  asm("v_cvt_pk_bf16_f32 %0, %1, %2" : "=v"(r) : "v"(lo), "v"(hi));
  return r;
}

__global__ __launch_bounds__(256, 2)
void qrnn3d_v14(const float* __restrict__ in, const float* __restrict__ Wg,
                const float* __restrict__ bg, float* __restrict__ out) {
  __shared__ __align__(16) short xs[4][SLICE_SH];   // 39,168 B

  const int tid = threadIdx.x;
  const int bid = blockIdx.x;
  // bijective XCD-chunked swizzle (512 blocks, 512%8==0)
  const int lin  = ((bid & 7) << 6) | (bid >> 3);
  const int b    = lin >> 7;                 // 4 batches x 128 tiles
  const int tile = lin & 127;
  const int h0   = (tile >> 2) * TILE_H;     // 32 h-tiles
  const int w0   = (tile & 3) * TILE_W;      // 4 w-tiles

  const int lane = tid & 63;
  const int wid  = tid >> 6;                 // wave 0..3 -> output row
  const int col  = lane & 31;                // MFMA N column / oc for A-frag
  const int half = lane >> 5;                // K half (ci 0-7 / 8-15)

  // ---- weights -> 27 A-frags ----
  bf16x8 wfrag[27];
#pragma unroll
  for (int tau = 0; tau < 27; ++tau) {
    bf16x8 f;
#pragma unroll
    for (int j = 0; j < 8; ++j)
      f[j] = (short)bf16_bits(Wg[col * 432 + (half * 8 + j) * 27 + tau]);
    wfrag[tau] = f;
  }

  // ---- bias-preloaded accumulator template + t-invariant store offsets ----
  f32x16 accInit;
  int voff[8];
#pragma unroll
  for (int r = 0; r < 8; ++r) {
    int oc = (r & 3) + 8 * (r >> 2) + 4 * half;          // 0..15
    accInit[r]     = bg[oc];
    accInit[r + 8] = bg[oc + 16];
    voff[r] = (b * CHID + oc) * CH_STRIDE + (h0 + wid) * 128 + (w0 + col);
  }

  // ---- staging precompute (t-invariant): unit = (pos, ci-quad) ----
  const float* gp[4];
  int  lso[4];
  bool stv[4], ldv[4];
#pragma unroll
  for (int i = 0; i < 4; ++i) {
    int p   = tid + i * 256;         // [0,1024)
    int q   = p & 15;
    int c4  = (p >> 4) & 3;
    int j   = p >> 6;
    int pos = j * 16 + q;            // [0,256)
    stv[i]  = (pos < SPOS);
    int hh  = pos / SW;
    int ww  = pos - hh * SW;
    int gh  = h0 + hh - 1, gw = w0 + ww - 1;
    ldv[i]  = stv[i] && ((unsigned)gh < 128u) && ((unsigned)gw < 128u);
    int sp  = ldv[i] ? (gh * 128 + gw) : 0;
    gp[i]   = in + (size_t)(b * CIN + c4 * 4) * CH_STRIDE + sp;
    lso[i]  = pos * PSTR + c4 * 4;   // shorts
  }

#define LOADV(tz, vv)                                                \
  do {                                                               \
    if ((tz) <= 30) {                                                \
      const int toff = (tz) * HW_;                                   \
      _Pragma("unroll")                                              \
      for (int i = 0; i < 4; ++i) {                                  \
        _Pragma("unroll")                                            \
        for (int k = 0; k < 4; ++k)                                  \
          vv[i][k] = ldv[i] ? gp[i][toff + k * CH_STRIDE] : 0.0f;    \
      }                                                              \
    } else {                                                         \
      _Pragma("unroll")                                              \
      for (int i = 0; i < 4; ++i) {                                  \
        _Pragma("unroll")                                            \
        for (int k = 0; k < 4; ++k) vv[i][k] = 0.0f;                 \
      }                                                              \
    }                                                                \
  } while (0)

#define STOREV(vv, slot)                                             \
  do {                                                               \
    short* dst = &xs[(slot)][0];                                     \
    _Pragma("unroll")                                                \
    for (int i = 0; i < 4; ++i) {                                    \
      if (stv[i]) {                                                  \
        uint2 u;                                                     \
        u.x = cvt_pk_bf16(vv[i][0], vv[i][1]);                       \
        u.y = cvt_pk_bf16(vv[i][2], vv[i][3]);                       \
        *reinterpret_cast<uint2*>(dst + lso[i]) = u;                 \
      }                                                              \
    }                                                                \
  } while (0)

  // THE ONE CHANGE vs R11 (123 us champion): barrier drains LDS ops only.
  // ds_writes are lgkm-counted (visibility preserved); the in-flight global
  // prefetch loads stay in flight across the barrier — their vmcnt is waited
  // on by the compiler at next step's STOREV use of the registers.
#define BARRIER()                                                    \
  do {                                                               \
    asm volatile("s_waitcnt lgkmcnt(0)" ::: "memory");               \
    __builtin_amdgcn_s_barrier();                                    \
  } while (0)

  // ---- compute geometry: 9 LDS read offsets (kh,kw), t-invariant ----
  int lb[9];
#pragma unroll
  for (int kh = 0; kh < 3; ++kh)
#pragma unroll
    for (int kw = 0; kw < 3; ++kw)
      lb[kh * 3 + kw] = ((wid + kh) * SW + (col + kw)) * PSTR + half * 8;

  float hst[8];
#pragma unroll
  for (int r = 0; r < 8; ++r) hst[r] = 0.0f;

  const float C_TANH = 2.8853900817779268f;   // 2*log2(e)
  const float C_SIG  = 1.4426950408889634f;   // log2(e)

  auto compute = [&](int t) {
    const short* base = &xs[0][0];
    const short* sA = base + ((t + 3) & 3) * SLICE_SH;   // slice t-1
    const short* sB = base + ((t    ) & 3) * SLICE_SH;   // slice t
    const short* sC = base + ((t + 1) & 3) * SLICE_SH;   // slice t+1

    f32x16 acc0 = accInit;
    f32x16 acc1;
#pragma unroll
    for (int i = 0; i < 16; ++i) acc1[i] = 0.0f;

#pragma unroll
    for (int kd = 0; kd < 3; ++kd) {
      const short* sp = (kd == 0) ? sA : (kd == 1) ? sB : sC;
#pragma unroll
      for (int u = 0; u < 9; ++u) {
        const int tau = kd * 9 + u;
        bf16x8 xb = *reinterpret_cast<const bf16x8*>(sp + lb[u]);
        if (tau & 1)
          acc1 = __builtin_amdgcn_mfma_f32_32x32x16_bf16(wfrag[tau], xb, acc1, 0, 0, 0);
        else
          acc0 = __builtin_amdgcn_mfma_f32_32x32x16_bf16(wfrag[tau], xb, acc0, 0, 0, 0);
      }
    }

    float* outT = out + (size_t)t * HW_;
#pragma unroll
    for (int r = 0; r < 8; ++r) {
      float zg = acc0[r] + acc1[r];
      float fg = acc0[r + 8] + acc1[r + 8];
      float ez = exp2f(zg * C_TANH);
      float z  = __builtin_fmaf(-2.0f, __builtin_amdgcn_rcpf(ez + 1.0f), 1.0f);
      float ef = exp2f(-fg * C_SIG);
      float f  = __builtin_amdgcn_rcpf(1.0f + ef);
      float h  = __builtin_fmaf(f, hst[r] - z, z);
      hst[r]   = h;
      outT[voff[r]] = h;
    }
  };

  // ---- prologue: slices 0,1 staged; slice 2 in regs; slot3 = zeros (slice -1)
  float vA[4][4], vB[4][4];
  LOADV(0, vA); STOREV(vA, 0);
  LOADV(1, vA); STOREV(vA, 1);
  LOADV(2, vA);
  for (int i = tid; i < SLICE_SH / 2; i += 256)
    reinterpret_cast<unsigned*>(&xs[3][0])[i] = 0u;
  BARRIER();

#pragma unroll 1
  for (int t = 0; t < 30; t += 2) {
    // even step: regs A hold slice t+2
    LOADV(t + 3, vB);                 // issue loads early
    STOREV(vA, (t + 2) & 3);
    compute(t);
    BARRIER();
    // odd step: regs B hold slice t+3
    LOADV(t + 4, vA);
    STOREV(vB, (t + 3) & 3);
    compute(t + 1);
    BARRIER();
  }
  compute(30);

#undef LOADV
#undef STOREV
#undef BARRIER
}

extern "C" void kernel_launch(void* const* d_in, const int* in_sizes, int n_in,
                              void* d_out, int out_size, void* d_ws, size_t ws_size,
                              hipStream_t stream) {
  const float* in = (const float*)d_in[0];
  const float* Wg = (const float*)d_in[1];
  const float* bg = (const float*)d_in[2];
  float* out      = (float*)d_out;
  (void)in_sizes; (void)n_in; (void)out_size; (void)d_ws; (void)ws_size;
  qrnn3d_v14<<<dim3(512), dim3(256), 0, stream>>>(in, Wg, bg, out);
}

// Round 15
// 119.216 us; speedup vs baseline: 1.9116x; 1.0536x over previous
//
#include <hip/hip_runtime.h>
#include <cstdint>
#include <cstddef>

#define CIN     16
#define CHID    16
#define T_DIM   31
#define HW_     16384            // 128*128
#define CH_STRIDE 507904         // 31*128*128
#define TILE_H  8
#define TILE_W  32
#define SH      10               // TILE_H + 2
#define SW      34               // TILE_W + 2
#define SPOS    (SH * SW)        // 340 positions
#define PSTR    24               // 48B/position: 16B-aligned ds_read_b128 (PSTR=20 costs 2x — R6/R8/R10)
#define SLICE_SH (SPOS * PSTR)   // 8160 shorts = 16,320 B
#define NSLOT   4                // 65,280 B LDS ring (< 64 KiB static limit)

typedef short bf16x8 __attribute__((ext_vector_type(8)));
typedef float f32x16 __attribute__((ext_vector_type(16)));

__device__ __forceinline__ unsigned bf16_bits(float x) {
  unsigned u = __builtin_bit_cast(unsigned, x);
  u += 0x7FFFu + ((u >> 16) & 1u);
  return u >> 16;
}
__device__ __forceinline__ unsigned cvt_pk_bf16(float lo, float hi) {
  unsigned r;
  asm("v_cvt_pk_bf16_f32 %0, %1, %2" : "=v"(r) : "v"(lo), "v"(hi));
  return r;
}

__global__ __launch_bounds__(512, 2)
void qrnn3d_v15(const float* __restrict__ in, const float* __restrict__ Wg,
                const float* __restrict__ bg, float* __restrict__ out) {
  __shared__ __align__(16) short xs[NSLOT][SLICE_SH];

  const int tid = threadIdx.x;
  const int bid = blockIdx.x;
  // bijective XCD-chunked swizzle (256 blocks, 256%8==0): XCD k gets 32
  // consecutive lin = 8 contiguous h-tiles x 4 w-tiles -> halo L2 sharing
  const int lin  = ((bid & 7) << 5) | (bid >> 3);
  const int b    = lin >> 6;                 // 4 batches x 64 tiles
  const int tile = lin & 63;
  const int h0   = (tile >> 2) * TILE_H;     // 16 h-tiles
  const int w0   = (tile & 3) * TILE_W;      // 4 w-tiles

  const int lane = tid & 63;
  const int wid  = tid >> 6;                 // wave 0..7 -> output row
  const int col  = lane & 31;                // MFMA N column / oc for A-frag
  const int half = lane >> 5;                // K half (ci 0-7 / 8-15)

  // ---- weights -> 27 A-frags ----
  bf16x8 wfrag[27];
#pragma unroll
  for (int tau = 0; tau < 27; ++tau) {
    bf16x8 f;
#pragma unroll
    for (int j = 0; j < 8; ++j)
      f[j] = (short)bf16_bits(Wg[col * 432 + (half * 8 + j) * 27 + tau]);
    wfrag[tau] = f;
  }

  // ---- bias-preloaded accumulator template + t-invariant store offsets ----
  f32x16 accInit;
  int voff[8];
#pragma unroll
  for (int r = 0; r < 8; ++r) {
    int oc = (r & 3) + 8 * (r >> 2) + 4 * half;          // 0..15
    accInit[r]     = bg[oc];
    accInit[r + 8] = bg[oc + 16];
    voff[r] = (b * CHID + oc) * CH_STRIDE + (h0 + wid) * 128 + (w0 + col);
  }

  // ---- staging precompute (t-invariant): unit = (pos, ci-quad), 3/thread ----
  const float* gp[3];
  int  lso[3];
  bool stv[3], ldv[3];
#pragma unroll
  for (int i = 0; i < 3; ++i) {
    int p   = tid + i * 512;         // [0,1536) covers 340*4=1360 units
    int q   = p & 15;
    int c4  = (p >> 4) & 3;
    int j   = p >> 6;
    int pos = j * 16 + q;            // [0,384)
    stv[i]  = (pos < SPOS);
    int hh  = pos / SW;
    int ww  = pos - hh * SW;
    int gh  = h0 + hh - 1, gw = w0 + ww - 1;
    ldv[i]  = stv[i] && ((unsigned)gh < 128u) && ((unsigned)gw < 128u);
    int sp  = ldv[i] ? (gh * 128 + gw) : 0;
    gp[i]   = in + (size_t)(b * CIN + c4 * 4) * CH_STRIDE + sp;
    lso[i]  = pos * PSTR + c4 * 4;   // shorts
  }

#define LOADV(tz, vv)                                                \
  do {                                                               \
    if ((tz) <= 30) {                                                \
      const int toff = (tz) * HW_;                                   \
      _Pragma("unroll")                                              \
      for (int i = 0; i < 3; ++i) {                                  \
        _Pragma("unroll")                                            \
        for (int k = 0; k < 4; ++k)                                  \
          vv[i][k] = ldv[i] ? gp[i][toff + k * CH_STRIDE] : 0.0f;    \
      }                                                              \
    } else {                                                         \
      _Pragma("unroll")                                              \
      for (int i = 0; i < 3; ++i) {                                  \
        _Pragma("unroll")                                            \
        for (int k = 0; k < 4; ++k) vv[i][k] = 0.0f;                 \
      }                                                              \
    }                                                                \
  } while (0)

#define STOREV(vv, slot)                                             \
  do {                                                               \
    short* dst = &xs[(slot)][0];                                     \
    _Pragma("unroll")                                                \
    for (int i = 0; i < 3; ++i) {                                    \
      if (stv[i]) {                                                  \
        uint2 u;                                                     \
        u.x = cvt_pk_bf16(vv[i][0], vv[i][1]);                       \
        u.y = cvt_pk_bf16(vv[i][2], vv[i][3]);                       \
        *reinterpret_cast<uint2*>(dst + lso[i]) = u;                 \
      }                                                              \
    }                                                                \
  } while (0)

  // ---- compute geometry: 9 LDS read offsets (kh,kw), t-invariant ----
  int lb[9];
#pragma unroll
  for (int kh = 0; kh < 3; ++kh)
#pragma unroll
    for (int kw = 0; kw < 3; ++kw)
      lb[kh * 3 + kw] = ((wid + kh) * SW + (col + kw)) * PSTR + half * 8;

  float hst[8];
#pragma unroll
  for (int r = 0; r < 8; ++r) hst[r] = 0.0f;

  const float C_TANH = 2.8853900817779268f;   // 2*log2(e)
  const float C_SIG  = 1.4426950408889634f;   // log2(e)

  auto compute = [&](int t) {
    const short* base = &xs[0][0];
    const short* sA = base + ((t + 3) & 3) * SLICE_SH;   // slice t-1
    const short* sB = base + ((t    ) & 3) * SLICE_SH;   // slice t
    const short* sC = base + ((t + 1) & 3) * SLICE_SH;   // slice t+1

    f32x16 acc0 = accInit;
    f32x16 acc1;
#pragma unroll
    for (int i = 0; i < 16; ++i) acc1[i] = 0.0f;

#pragma unroll
    for (int kd = 0; kd < 3; ++kd) {
      const short* sp = (kd == 0) ? sA : (kd == 1) ? sB : sC;
#pragma unroll
      for (int u = 0; u < 9; ++u) {
        const int tau = kd * 9 + u;
        bf16x8 xb = *reinterpret_cast<const bf16x8*>(sp + lb[u]);
        if (tau & 1)
          acc1 = __builtin_amdgcn_mfma_f32_32x32x16_bf16(wfrag[tau], xb, acc1, 0, 0, 0);
        else
          acc0 = __builtin_amdgcn_mfma_f32_32x32x16_bf16(wfrag[tau], xb, acc0, 0, 0, 0);
      }
    }

    float* outT = out + (size_t)t * HW_;
#pragma unroll
    for (int r = 0; r < 8; ++r) {
      float zg = acc0[r] + acc1[r];
      float fg = acc0[r + 8] + acc1[r + 8];
      float ez = exp2f(zg * C_TANH);
      float z  = __builtin_fmaf(-2.0f, __builtin_amdgcn_rcpf(ez + 1.0f), 1.0f);
      float ef = exp2f(-fg * C_SIG);
      float f  = __builtin_amdgcn_rcpf(1.0f + ef);
      float h  = __builtin_fmaf(f, hst[r] - z, z);
      hst[r]   = h;
      outT[voff[r]] = h;
    }
  };

  // ---- prologue: slices 0,1 staged; slice 2 in regs; slot3 = zeros (slice -1)
  float vA[3][4], vB[3][4];
  LOADV(0, vA); STOREV(vA, 0);
  LOADV(1, vA); STOREV(vA, 1);
  LOADV(2, vA);
  for (int i = tid; i < SLICE_SH / 2; i += 512)
    reinterpret_cast<unsigned*>(&xs[3][0])[i] = 0u;
  __syncthreads();

#pragma unroll 1
  for (int t = 0; t < 30; t += 2) {
    // even step: regs A hold slice t+2
    LOADV(t + 3, vB);                 // issue loads early
    STOREV(vA, (t + 2) & 3);
    compute(t);
    __syncthreads();
    // odd step: regs B hold slice t+3
    LOADV(t + 4, vA);
    STOREV(vB, (t + 3) & 3);
    compute(t + 1);
    __syncthreads();
  }
  compute(30);

#undef LOADV
#undef STOREV
}

extern "C" void kernel_launch(void* const* d_in, const int* in_sizes, int n_in,
                              void* d_out, int out_size, void* d_ws, size_t ws_size,
                              hipStream_t stream) {
  const float* in = (const float*)d_in[0];
  const float* Wg = (const float*)d_in[1];
  const float* bg = (const float*)d_in[2];
  float* out      = (float*)d_out;
  (void)in_sizes; (void)n_in; (void)out_size; (void)d_ws; (void)ws_size;
  qrnn3d_v15<<<dim3(256), dim3(512), 0, stream>>>(in, Wg, bg, out);
}